// Round 6
// baseline (658.299 us; speedup 1.0000x reference)
//
#include <hip/hip_runtime.h>
#include <math.h>

#define NLAT 64
#define NLON 128
#define MODEL_DIM 66
#define LEARN 64
#define KPL 8
#define KSIZE 7
#define NFREQ 65
#define TOTAL_K 24
#define HEAD_HID 32
#define FFN_HID 128
#define MAXU 20

#define TWO_PI_OVER_N 0.04908738521234052f

typedef unsigned long long u64;

static __device__ __forceinline__ float gelu_f(float v) {
    return 0.5f * v * (1.0f + erff(v * 0.7071067811865475f));
}

// K0: per-(k,l) lat nonzero masks by scanning psi. Block per kl.
__global__ void k0_mask(const float* __restrict__ psi, u64* __restrict__ nzm) {
    const int kl = blockIdx.x;          // 448
    const int t = threadIdx.x;          // 256
    const int i = t >> 2, q = t & 3;
    const float4* p = (const float4*)(psi + ((size_t)kl * 64 + i) * NLON + q * 32);
    bool nz = false;
#pragma unroll
    for (int u = 0; u < 8; ++u) {
        const float4 v = p[u];
        nz = nz | (v.x != 0.f) | (v.y != 0.f) | (v.z != 0.f) | (v.w != 0.f);
    }
    __shared__ unsigned char fl[64];
    if (t < 64) fl[t] = 0;
    __syncthreads();
    if (nz) fl[i] = 1;
    __syncthreads();
    if (t == 0) {
        u64 m = 0;
        for (int ii = 0; ii < 64; ++ii) if (fl[ii]) m |= (1ull << ii);
        nzm[kl] = m;
    }
}

// K1: rfft over lon of the 64 learned channels of x. Xh[ch][i][f]. Exact tables.
__global__ void k1_fft_x(const float* __restrict__ x, float2* __restrict__ Xh) {
    const int row = blockIdx.x;        // ch*64 + i
    const int ch = row >> 6;
    const int i = row & 63;
    const int t = threadIdx.x;         // 0..127
    __shared__ float sx[NLON];
    __shared__ float ct[NLON], st[NLON];
    float s, c;
    sincosf(TWO_PI_OVER_N * (float)t, &s, &c);
    ct[t] = c; st[t] = s;
    sx[t] = x[(size_t)(i * NLON + t) * MODEL_DIM + ch];
    __syncthreads();
    if (t < NFREQ) {
        float re = 0.f, im = 0.f;
        for (int p = 0; p < NLON; ++p) {
            const int m = (t * p) & 127;
            const float v = sx[p];
            re = fmaf(v, ct[m], re);
            im = fmaf(-v, st[m], im);
        }
        Xh[(size_t)row * NFREQ + t] = make_float2(re, im);
    }
}

// K2: conj(rfft(psi)) into dense pack Pp[l][j][k][f] (j over the per-l union
// lat list). One block per (k,l); zero-fills union rows not in this k's mask.
__global__ void k2_dft(const float* __restrict__ psi, const u64* __restrict__ nzm,
                       float2* __restrict__ Pp) {
    const int kl = blockIdx.x;          // 448
    const int k = kl >> 6, l = kl & 63;
    const int t = threadIdx.x;          // 0..127
    const u64 mk = nzm[kl];
    u64 uni = 0;
#pragma unroll
    for (int kk = 0; kk < KSIZE; ++kk) uni |= nzm[kk * 64 + l];
    __shared__ float sx[NLON];
    __shared__ float ct[NLON], st[NLON];
    float s, c;
    sincosf(TWO_PI_OVER_N * (float)t, &s, &c);
    ct[t] = c; st[t] = s;
    __syncthreads();
    int j = 0;
    for (u64 m = uni; m; m &= m - 1, ++j) {
        if (j >= MAXU) break;
        const int i = __builtin_ctzll(m);
        float2* dst = Pp + ((size_t)(l * MAXU + j) * 8 + k) * NFREQ;
        const bool live = (mk >> i) & 1ull;
        if (live) {                     // uniform branch: barriers legal
            __syncthreads();
            sx[t] = psi[((size_t)kl * 64 + i) * NLON + t];
            __syncthreads();
        }
        if (t < NFREQ) {
            if (live) {
                float re = 0.f, im = 0.f;
                for (int p = 0; p < NLON; ++p) {
                    const int m2 = (t * p) & 127;
                    const float u = sx[p];
                    re = fmaf(u, ct[m2], re);   // conj(rfft): e^{+i theta}
                    im = fmaf(u, st[m2], im);
                }
                dst[t] = make_float2(re, im);
            } else {
                dst[t] = make_float2(0.f, 0.f);
            }
        }
    }
}

// K3 v5: software-pipelined dense j-loop (double-buffered xv/pv registers),
// 256-thread blocks. In [ch][c][i][f]; Pp [l][j][k][f]; Out [ch][o][l][f].
// Blocks 0..15 handle Nyquist f=64; 16..1039 main.
template <int CIN, int CHALF>
__global__ __launch_bounds__(256, 3) void k3_contract(
    const float2* __restrict__ Pp, const float2* __restrict__ In,
    const float* __restrict__ w, const float* __restrict__ bias,
    const u64* __restrict__ nzm, float2* __restrict__ Out) {
    const int bid = blockIdx.x;
    int f, ch, l;
    if (bid >= 16) {
        const int b = bid - 16;
        f = threadIdx.x;
        l = ((b & 7) << 3) | ((b >> 3) & 7);   // XCD swizzle on l-octile
        ch = ((b >> 6) << 2) + threadIdx.y;
    } else {
        f = 64;
        ch = threadIdx.x;
        l = (bid << 2) + threadIdx.y;
    }
    u64 uni = 0;
#pragma unroll
    for (int k = 0; k < KSIZE; ++k) uni |= nzm[k * 64 + l];
    int U = __popcll(uni);
    if (U > MAXU) U = MAXU;

    const float2* inB = In + (size_t)ch * (CIN * NLAT * NFREQ) + f;
    const float2* pB = Pp + (size_t)l * (MAXU * 8 * NFREQ) + f;

    float2 acc[KPL];
#pragma unroll
    for (int o = 0; o < KPL; ++o) acc[o] = make_float2(0.f, 0.f);

    for (int cb = 0; cb < CIN; cb += CHALF) {
        float2 zs[CHALF][KSIZE];
#pragma unroll
        for (int c = 0; c < CHALF; ++c)
#pragma unroll
            for (int k = 0; k < KSIZE; ++k) zs[c][k] = make_float2(0.f, 0.f);

        float2 xa[CHALF], pa[KSIZE], xb[CHALF], pb2[KSIZE];
        u64 m = uni;
        {
            const int i = __builtin_ctzll(m); m &= m - 1;
#pragma unroll
            for (int c = 0; c < CHALF; ++c) xa[c] = inB[(size_t)((cb + c) * NLAT + i) * NFREQ];
#pragma unroll
            for (int k = 0; k < KSIZE; ++k) pa[k] = pB[(size_t)k * NFREQ];
        }
        int j = 0;
        while (true) {
            if (j + 1 < U) {           // prefetch j+1 into B while computing A
                const int i = __builtin_ctzll(m); m &= m - 1;
#pragma unroll
                for (int c = 0; c < CHALF; ++c) xb[c] = inB[(size_t)((cb + c) * NLAT + i) * NFREQ];
#pragma unroll
                for (int k = 0; k < KSIZE; ++k) pb2[k] = pB[(size_t)((j + 1) * 8 + k) * NFREQ];
            }
#pragma unroll
            for (int c = 0; c < CHALF; ++c)
#pragma unroll
                for (int k = 0; k < KSIZE; ++k) {
                    zs[c][k].x = fmaf(pa[k].x, xa[c].x, fmaf(-pa[k].y, xa[c].y, zs[c][k].x));
                    zs[c][k].y = fmaf(pa[k].x, xa[c].y, fmaf(pa[k].y, xa[c].x, zs[c][k].y));
                }
            if (++j >= U) break;
            if (j + 1 < U) {           // prefetch j+1 into A while computing B
                const int i = __builtin_ctzll(m); m &= m - 1;
#pragma unroll
                for (int c = 0; c < CHALF; ++c) xa[c] = inB[(size_t)((cb + c) * NLAT + i) * NFREQ];
#pragma unroll
                for (int k = 0; k < KSIZE; ++k) pa[k] = pB[(size_t)((j + 1) * 8 + k) * NFREQ];
            }
#pragma unroll
            for (int c = 0; c < CHALF; ++c)
#pragma unroll
                for (int k = 0; k < KSIZE; ++k) {
                    zs[c][k].x = fmaf(pb2[k].x, xb[c].x, fmaf(-pb2[k].y, xb[c].y, zs[c][k].x));
                    zs[c][k].y = fmaf(pb2[k].x, xb[c].y, fmaf(pb2[k].y, xb[c].x, zs[c][k].y));
                }
            if (++j >= U) break;
        }
#pragma unroll
        for (int o = 0; o < KPL; ++o)
#pragma unroll
            for (int c = 0; c < CHALF; ++c)
#pragma unroll
                for (int k = 0; k < KSIZE; ++k) {
                    const float wv = w[(o * CIN + cb + c) * KSIZE + k];
                    acc[o].x = fmaf(wv, zs[c][k].x, acc[o].x);
                    acc[o].y = fmaf(wv, zs[c][k].y, acc[o].y);
                }
    }
#pragma unroll
    for (int o = 0; o < KPL; ++o) {
        float2 v = acc[o];
        if (f == 0) v.x += 128.0f * bias[o];   // spatial bias == DC-bin offset
        Out[((size_t)(ch * KPL + o) * NLAT + l) * NFREQ + f] = v;
    }
}

// K4 v2: irfft as LDS-table sum with Nyquist symmetry. Lane = p (0..63);
// outputs p and p+64 share table entries via e^{i pi f} = (-1)^f, so we
// accumulate even-f / odd-f partial sums: out[p]=Se+So, out[p+64]=Se-So.
// 2 rows per wave; row spectra read as wave-uniform scalar loads.
__global__ __launch_bounds__(256, 4) void k4_irfft(const float2* __restrict__ Ch,
                                                   float* __restrict__ dbuf, int lvl) {
    __shared__ float2 tab[64 * 64];    // [f][p], f=0 unused; 32 KB
    const int t = threadIdx.x;         // 256
    for (int idx = t; idx < 64 * 64; idx += 256) {
        const int ff = idx >> 6, p = idx & 63;
        float s, c;
        sincosf(TWO_PI_OVER_N * (float)((ff * p) & 127), &s, &c);
        tab[idx] = make_float2(c, s);
    }
    __syncthreads();
    const int wv = (blockIdx.x << 2) | (t >> 6);   // wave id, 2 rows each
    const int lane = t & 63;                       // = p
    const int r0 = wv << 1;
    const float2* R0 = Ch + (size_t)r0 * NFREQ;
    const float2* R1 = R0 + NFREQ;
    float Se0 = 0.f, So0 = 0.f, Se1 = 0.f, So1 = 0.f;
    for (int ff = 1; ff < 64; ff += 2) {           // odd f -> So
        const float2 cs = tab[(ff << 6) | lane];
        const float2 a0 = R0[ff], a1 = R1[ff];
        So0 = fmaf(a0.x, cs.x, So0); So0 = fmaf(-a0.y, cs.y, So0);
        So1 = fmaf(a1.x, cs.x, So1); So1 = fmaf(-a1.y, cs.y, So1);
    }
    for (int ff = 2; ff < 64; ff += 2) {           // even f -> Se
        const float2 cs = tab[(ff << 6) | lane];
        const float2 a0 = R0[ff], a1 = R1[ff];
        Se0 = fmaf(a0.x, cs.x, Se0); Se0 = fmaf(-a0.y, cs.y, Se0);
        Se1 = fmaf(a1.x, cs.x, Se1); Se1 = fmaf(-a1.y, cs.y, Se1);
    }
    const float sgp = (lane & 1) ? -1.f : 1.f;
    const float b0 = R0[0].x + sgp * R0[64].x;
    const float b1 = R1[0].x + sgp * R1[64].x;
    // rows r in [ch][o][l] order -> dbuf [l][ch][K][p]
#pragma unroll
    for (int rr = 0; rr < 2; ++rr) {
        const int r = r0 + rr;
        const int ch = r >> 9, o = (r >> 6) & 7, l = r & 63;
        float* dst = dbuf + (((size_t)l * 64 + ch) * TOTAL_K + lvl * 8 + o) * NLON;
        const float bb = rr ? b1 : b0;
        const float se = rr ? Se1 : Se0, so = rr ? So1 : So0;
        dst[lane]      = (bb + 2.f * (se + so)) * (1.f / 128.f);
        dst[lane + 64] = (bb + 2.f * (se - so)) * (1.f / 128.f);
    }
}

// K5: fused head-MLP + residual + FFN + residual. Block = (l, 8-lon tile).
__global__ __launch_bounds__(256, 1) void k5_head_ffn(
    const float* __restrict__ dbuf, const float* __restrict__ x,
    const float* __restrict__ hw1, const float* __restrict__ hb1,
    const float* __restrict__ hw2, const float* __restrict__ hb2,
    const float* __restrict__ fw0, const float* __restrict__ fb0,
    const float* __restrict__ fw1, const float* __restrict__ fb1,
    float* __restrict__ out) {
    const int l = blockIdx.x;
    const int pt = blockIdx.y;
    const int t = threadIdx.x;     // 256
    const int pos = t >> 5;        // 0..7
    const int lane = t & 31;
    const int p = pt * 8 + pos;

    __shared__ float sf[8][1537];          // feats per pos: [ch*24+K]
    __shared__ float sxl2[8][LEARN];
    __shared__ float sh[8][FFN_HID];

    for (int idx = t; idx < 1536 * 8; idx += 256) {
        const int row = idx >> 3;
        const int pp = idx & 7;
        sf[pp][row] = dbuf[((size_t)l * 1536 + row) * NLON + pt * 8 + pp];
    }
    __syncthreads();

#pragma unroll
    for (int s2 = 0; s2 < 2; ++s2) {
        const int ch = lane + 32 * s2;
        const int n = ch >> 4;
        float fr[TOTAL_K];
#pragma unroll
        for (int k = 0; k < TOTAL_K; ++k) fr[k] = sf[pos][ch * TOTAL_K + k];
        float ho = hb2[n];
        for (int m = 0; m < HEAD_HID; ++m) {
            float a = hb1[n * HEAD_HID + m];
#pragma unroll
            for (int k = 0; k < TOTAL_K; ++k)
                a = fmaf(fr[k], hw1[(n * TOTAL_K + k) * HEAD_HID + m], a);
            ho = fmaf(gelu_f(a), hw2[n * HEAD_HID + m], ho);
        }
        sxl2[pos][ch] = ho + x[(l * NLON + p) * MODEL_DIM + ch];
    }
    __syncthreads();

    const float sc0 = x[(l * NLON + p) * MODEL_DIM + 64];
    const float sc1 = x[(l * NLON + p) * MODEL_DIM + 65];

#pragma unroll
    for (int mm = 0; mm < 4; ++mm) {
        const int m = lane + 32 * mm;
        float a = fb0[m];
        for (int k = 0; k < LEARN; ++k)
            a = fmaf(sxl2[pos][k], fw0[k * FFN_HID + m], a);
        a = fmaf(sc0, fw0[64 * FFN_HID + m], a);
        a = fmaf(sc1, fw0[65 * FFN_HID + m], a);
        sh[pos][m] = gelu_f(a);
    }
    __syncthreads();

#pragma unroll
    for (int s2 = 0; s2 < 2; ++s2) {
        const int dch = lane + 32 * s2;
        float a = fb1[dch];
        for (int m = 0; m < FFN_HID; ++m)
            a = fmaf(sh[pos][m], fw1[m * LEARN + dch], a);
        out[(l * NLON + p) * MODEL_DIM + dch] = a + sxl2[pos][dch];
    }
    if (lane < 2) out[(l * NLON + p) * MODEL_DIM + 64 + lane] = lane ? sc1 : sc0;
}

extern "C" void kernel_launch(void* const* d_in, const int* in_sizes, int n_in,
                              void* d_out, int out_size, void* d_ws, size_t ws_size,
                              hipStream_t stream) {
    (void)in_sizes; (void)n_in; (void)out_size; (void)ws_size;
    const float* x = (const float*)d_in[0];
    const float* psi[3] = {(const float*)d_in[1], (const float*)d_in[2], (const float*)d_in[3]};
    const float* w[3] = {(const float*)d_in[4], (const float*)d_in[6], (const float*)d_in[8]};
    const float* b[3] = {(const float*)d_in[5], (const float*)d_in[7], (const float*)d_in[9]};
    const float* hw1 = (const float*)d_in[10];
    const float* hb1 = (const float*)d_in[11];
    const float* hw2 = (const float*)d_in[12];
    const float* hb2 = (const float*)d_in[13];
    const float* fw0 = (const float*)d_in[14];
    const float* fb0 = (const float*)d_in[15];
    const float* fw1 = (const float*)d_in[16];
    const float* fb1 = (const float*)d_in[17];
    float* out = (float*)d_out;

    // workspace carve-up, ~92 MB total
    float2* Xh = (float2*)d_ws;                 // 64*64*65            = 266240
    float2* Pp = Xh + 266240;                   // 64*20*8*65          = 665600
    float2* bufA = Pp + 665600;                 // 64*8*64*65          = 2129920
    float2* bufB = bufA + 2129920;              // 64*8*64*65
    float* dbuf = (float*)(bufB + 2129920);     // 64*64*24*128 floats
    u64* nzm = (u64*)(dbuf + (size_t)64 * 64 * 24 * 128);   // 448 masks

    k1_fft_x<<<dim3(64 * 64), dim3(128), 0, stream>>>(x, Xh);

    for (int lvl = 0; lvl < 3; ++lvl) {
        k0_mask<<<dim3(448), dim3(256), 0, stream>>>(psi[lvl], nzm);
        k2_dft<<<dim3(448), dim3(128), 0, stream>>>(psi[lvl], nzm, Pp);
        const float2* ob;
        if (lvl == 0) {
            k3_contract<1, 1><<<dim3(1040), dim3(64, 4), 0, stream>>>(Pp, Xh, w[0], b[0], nzm, bufA);
            ob = bufA;
        } else if (lvl == 1) {
            k3_contract<8, 4><<<dim3(1040), dim3(64, 4), 0, stream>>>(Pp, bufA, w[1], b[1], nzm, bufB);
            ob = bufB;
        } else {
            k3_contract<8, 4><<<dim3(1040), dim3(64, 4), 0, stream>>>(Pp, bufB, w[2], b[2], nzm, bufA);
            ob = bufA;
        }
        k4_irfft<<<dim3(4096), dim3(256), 0, stream>>>(ob, dbuf, lvl);
    }

    k5_head_ffn<<<dim3(64, 16), dim3(256), 0, stream>>>(
        dbuf, x, hw1, hb1, hw2, hb2, fw0, fb0, fw1, fb1, out);
}

// Round 7
// 549.962 us; speedup vs baseline: 1.1970x; 1.1970x over previous
//
#include <hip/hip_runtime.h>
#include <math.h>

#define NLAT 64
#define NLON 128
#define MODEL_DIM 66
#define LEARN 64
#define KPL 8
#define KSIZE 7
#define NFREQ 65
#define FPAD 72            // padded spectrum row: 72 float2 = 576 B = 9 lines
#define TOTAL_K 24
#define HEAD_HID 32
#define FFN_HID 128
#define MAXU 20

#define TWO_PI_OVER_N 0.04908738521234052f

typedef unsigned long long u64;

static __device__ __forceinline__ float gelu_f(float v) {
    return 0.5f * v * (1.0f + erff(v * 0.7071067811865475f));
}

// K0: per-(k,l) lat nonzero masks by scanning psi. Block per kl.
__global__ void k0_mask(const float* __restrict__ psi, u64* __restrict__ nzm) {
    const int kl = blockIdx.x;          // 448
    const int t = threadIdx.x;          // 256
    const int i = t >> 2, q = t & 3;
    const float4* p = (const float4*)(psi + ((size_t)kl * 64 + i) * NLON + q * 32);
    bool nz = false;
#pragma unroll
    for (int u = 0; u < 8; ++u) {
        const float4 v = p[u];
        nz = nz | (v.x != 0.f) | (v.y != 0.f) | (v.z != 0.f) | (v.w != 0.f);
    }
    __shared__ unsigned char fl[64];
    if (t < 64) fl[t] = 0;
    __syncthreads();
    if (nz) fl[i] = 1;
    __syncthreads();
    if (t == 0) {
        u64 m = 0;
        for (int ii = 0; ii < 64; ++ii) if (fl[ii]) m |= (1ull << ii);
        nzm[kl] = m;
    }
}

// K1: rfft over lon of the 64 learned channels of x. Xh[ch][i][FPAD].
__global__ void k1_fft_x(const float* __restrict__ x, float2* __restrict__ Xh) {
    const int row = blockIdx.x;        // ch*64 + i
    const int ch = row >> 6;
    const int i = row & 63;
    const int t = threadIdx.x;         // 0..127
    __shared__ float sx[NLON];
    __shared__ float ct[NLON], st[NLON];
    float s, c;
    sincosf(TWO_PI_OVER_N * (float)t, &s, &c);
    ct[t] = c; st[t] = s;
    sx[t] = x[(size_t)(i * NLON + t) * MODEL_DIM + ch];
    __syncthreads();
    if (t < NFREQ) {
        float re = 0.f, im = 0.f;
        for (int p = 0; p < NLON; ++p) {
            const int m = (t * p) & 127;
            const float v = sx[p];
            re = fmaf(v, ct[m], re);
            im = fmaf(-v, st[m], im);
        }
        Xh[(size_t)row * FPAD + t] = make_float2(re, im);
    }
}

// K2: conj(rfft(psi)) into dense pack Pp[l][j][k][65] (compact, contiguous per
// l for LDS staging). Zero-fills union rows not in this k's mask.
__global__ void k2_dft(const float* __restrict__ psi, const u64* __restrict__ nzm,
                       float2* __restrict__ Pp) {
    const int kl = blockIdx.x;          // 448
    const int k = kl >> 6, l = kl & 63;
    const int t = threadIdx.x;          // 0..127
    const u64 mk = nzm[kl];
    u64 uni = 0;
#pragma unroll
    for (int kk = 0; kk < KSIZE; ++kk) uni |= nzm[kk * 64 + l];
    __shared__ float sx[NLON];
    __shared__ float ct[NLON], st[NLON];
    float s, c;
    sincosf(TWO_PI_OVER_N * (float)t, &s, &c);
    ct[t] = c; st[t] = s;
    __syncthreads();
    int j = 0;
    for (u64 m = uni; m; m &= m - 1, ++j) {
        if (j >= MAXU) break;
        const int i = __builtin_ctzll(m);
        float2* dst = Pp + ((size_t)(l * MAXU + j) * KSIZE + k) * NFREQ;
        const bool live = (mk >> i) & 1ull;
        if (live) {                     // uniform branch: barriers legal
            __syncthreads();
            sx[t] = psi[((size_t)kl * 64 + i) * NLON + t];
            __syncthreads();
        }
        if (t < NFREQ) {
            if (live) {
                float re = 0.f, im = 0.f;
                for (int p = 0; p < NLON; ++p) {
                    const int m2 = (t * p) & 127;
                    const float u = sx[p];
                    re = fmaf(u, ct[m2], re);   // conj(rfft): e^{+i theta}
                    im = fmaf(u, st[m2], im);
                }
                dst[t] = make_float2(re, im);
            } else {
                dst[t] = make_float2(0.f, 0.f);
            }
        }
    }
}

// K3 v6: per-l LDS staging of the psi pack; low-VGPR inner loop.
// In [ch][c][i][FPAD]; Pp [l][j][k][65]; Out [ch][o][l][FPAD].
// Blocks 0..7: Nyquist f=64 (wave = one l). Blocks 8..519: main, one l each,
// 512 thr = (64 f, 8 ch). c outermost: In read exactly once.
template <int CIN>
__global__ __launch_bounds__(512) void k3_contract(
    const float2* __restrict__ Pp, const float2* __restrict__ In,
    const float* __restrict__ w, const float* __restrict__ bias,
    const u64* __restrict__ nzm, float2* __restrict__ Out) {
    __shared__ float2 sP[MAXU * KSIZE * NFREQ];   // 72.8 KB
    const int bid = blockIdx.x;
    const int tx = threadIdx.x, ty = threadIdx.y;
    const int tid = ty * 64 + tx;

    if (bid >= 8) {
        // ---------- main path: f = tx, ch = chg*8+ty, one l ----------
        const int b = bid - 8;
        const int l = ((b & 7) << 3) | ((b >> 3) & 7);   // XCD swizzle
        const int ch = ((b >> 6) << 3) + ty;
        const int f = tx;
        u64 uni = 0;
#pragma unroll
        for (int k = 0; k < KSIZE; ++k) uni |= nzm[k * 64 + l];
        int U = __popcll(uni);
        if (U > MAXU) U = MAXU;

        const float2* PpL = Pp + (size_t)l * (MAXU * KSIZE * NFREQ);
        const int nstage = U * (KSIZE * NFREQ);
        for (int idx = tid; idx < nstage; idx += 512) sP[idx] = PpL[idx];
        __syncthreads();

        float2 acc[KPL];
#pragma unroll
        for (int o = 0; o < KPL; ++o) acc[o] = make_float2(0.f, 0.f);

        for (int c = 0; c < CIN; ++c) {
            const float2* inC = In + ((size_t)(ch * CIN + c) * NLAT) * FPAD + f;
            float2 zs[KSIZE];
#pragma unroll
            for (int k = 0; k < KSIZE; ++k) zs[k] = make_float2(0.f, 0.f);

            u64 m = uni;
            int i = __builtin_ctzll(m); m &= m - 1;
            float2 xv = inC[(size_t)i * FPAD];
            int j = 0;
            while (true) {
                float2 xn;
                const bool more = (j + 1 < U);
                if (more) {
                    i = __builtin_ctzll(m); m &= m - 1;
                    xn = inC[(size_t)i * FPAD];
                }
#pragma unroll
                for (int k = 0; k < KSIZE; ++k) {
                    const float2 pv = sP[(j * KSIZE + k) * NFREQ + f];
                    zs[k].x = fmaf(pv.x, xv.x, fmaf(-pv.y, xv.y, zs[k].x));
                    zs[k].y = fmaf(pv.x, xv.y, fmaf(pv.y, xv.x, zs[k].y));
                }
                ++j;
                if (!more) break;
                xv = xn;
            }
#pragma unroll
            for (int o = 0; o < KPL; ++o)
#pragma unroll
                for (int k = 0; k < KSIZE; ++k) {
                    const float wv = w[(o * CIN + c) * KSIZE + k];
                    acc[o].x = fmaf(wv, zs[k].x, acc[o].x);
                    acc[o].y = fmaf(wv, zs[k].y, acc[o].y);
                }
        }
#pragma unroll
        for (int o = 0; o < KPL; ++o) {
            float2 v = acc[o];
            if (f == 0) v.x += 128.0f * bias[o];   // spatial bias == DC-bin offset
            Out[((size_t)(ch * KPL + o) * NLAT + l) * FPAD + f] = v;
        }
    } else {
        // ---------- Nyquist path: f=64, ch = tx, wave = one l (ty) ----------
        const int l = (bid << 3) + ty;
        const int ch = tx;
        u64 uni = 0;
#pragma unroll
        for (int k = 0; k < KSIZE; ++k) uni |= nzm[k * 64 + l];
        int U = __popcll(uni);
        if (U > MAXU) U = MAXU;

        const float2* PpL = Pp + (size_t)l * (MAXU * KSIZE * NFREQ);
        float2* sN = sP + ty * (MAXU * KSIZE);     // per-wave 140-slot slice
        for (int idx = tx; idx < U * KSIZE; idx += 64)
            sN[idx] = PpL[(size_t)idx * NFREQ + 64];
        __syncthreads();

        float2 acc[KPL];
#pragma unroll
        for (int o = 0; o < KPL; ++o) acc[o] = make_float2(0.f, 0.f);

        for (int c = 0; c < CIN; ++c) {
            const float2* inC = In + ((size_t)(ch * CIN + c) * NLAT) * FPAD + 64;
            float2 zs[KSIZE];
#pragma unroll
            for (int k = 0; k < KSIZE; ++k) zs[k] = make_float2(0.f, 0.f);
            u64 m = uni;
            for (int j = 0; j < U; ++j) {
                const int i = __builtin_ctzll(m); m &= m - 1;
                const float2 xv = inC[(size_t)i * FPAD];
#pragma unroll
                for (int k = 0; k < KSIZE; ++k) {
                    const float2 pv = sN[j * KSIZE + k];
                    zs[k].x = fmaf(pv.x, xv.x, fmaf(-pv.y, xv.y, zs[k].x));
                    zs[k].y = fmaf(pv.x, xv.y, fmaf(pv.y, xv.x, zs[k].y));
                }
            }
#pragma unroll
            for (int o = 0; o < KPL; ++o)
#pragma unroll
                for (int k = 0; k < KSIZE; ++k) {
                    const float wv = w[(o * CIN + c) * KSIZE + k];
                    acc[o].x = fmaf(wv, zs[k].x, acc[o].x);
                    acc[o].y = fmaf(wv, zs[k].y, acc[o].y);
                }
        }
#pragma unroll
        for (int o = 0; o < KPL; ++o)
            Out[((size_t)(ch * KPL + o) * NLAT + l) * FPAD + 64] = acc[o];
    }
}

// K4 v2: irfft via LDS table + Nyquist symmetry; Ch rows at stride FPAD.
__global__ __launch_bounds__(256, 4) void k4_irfft(const float2* __restrict__ Ch,
                                                   float* __restrict__ dbuf, int lvl) {
    __shared__ float2 tab[64 * 64];    // [f][p]; 32 KB
    const int t = threadIdx.x;         // 256
    for (int idx = t; idx < 64 * 64; idx += 256) {
        const int ff = idx >> 6, p = idx & 63;
        float s, c;
        sincosf(TWO_PI_OVER_N * (float)((ff * p) & 127), &s, &c);
        tab[idx] = make_float2(c, s);
    }
    __syncthreads();
    const int wv = (blockIdx.x << 2) | (t >> 6);   // wave id, 2 rows each
    const int lane = t & 63;                       // = p
    const int r0 = wv << 1;
    const float2* R0 = Ch + (size_t)r0 * FPAD;
    const float2* R1 = R0 + FPAD;
    float Se0 = 0.f, So0 = 0.f, Se1 = 0.f, So1 = 0.f;
    for (int ff = 1; ff < 64; ff += 2) {           // odd f -> So
        const float2 cs = tab[(ff << 6) | lane];
        const float2 a0 = R0[ff], a1 = R1[ff];
        So0 = fmaf(a0.x, cs.x, So0); So0 = fmaf(-a0.y, cs.y, So0);
        So1 = fmaf(a1.x, cs.x, So1); So1 = fmaf(-a1.y, cs.y, So1);
    }
    for (int ff = 2; ff < 64; ff += 2) {           // even f -> Se
        const float2 cs = tab[(ff << 6) | lane];
        const float2 a0 = R0[ff], a1 = R1[ff];
        Se0 = fmaf(a0.x, cs.x, Se0); Se0 = fmaf(-a0.y, cs.y, Se0);
        Se1 = fmaf(a1.x, cs.x, Se1); Se1 = fmaf(-a1.y, cs.y, Se1);
    }
    const float sgp = (lane & 1) ? -1.f : 1.f;
    const float b0 = R0[0].x + sgp * R0[64].x;
    const float b1 = R1[0].x + sgp * R1[64].x;
    // rows r in [ch][o][l] order -> dbuf [l][ch][K][p]
#pragma unroll
    for (int rr = 0; rr < 2; ++rr) {
        const int r = r0 + rr;
        const int ch = r >> 9, o = (r >> 6) & 7, l = r & 63;
        float* dst = dbuf + (((size_t)l * 64 + ch) * TOTAL_K + lvl * 8 + o) * NLON;
        const float bb = rr ? b1 : b0;
        const float se = rr ? Se1 : Se0, so = rr ? So1 : So0;
        dst[lane]      = (bb + 2.f * (se + so)) * (1.f / 128.f);
        dst[lane + 64] = (bb + 2.f * (se - so)) * (1.f / 128.f);
    }
}

// K5: fused head-MLP + residual + FFN + residual. Block = (l, 8-lon tile).
__global__ __launch_bounds__(256, 1) void k5_head_ffn(
    const float* __restrict__ dbuf, const float* __restrict__ x,
    const float* __restrict__ hw1, const float* __restrict__ hb1,
    const float* __restrict__ hw2, const float* __restrict__ hb2,
    const float* __restrict__ fw0, const float* __restrict__ fb0,
    const float* __restrict__ fw1, const float* __restrict__ fb1,
    float* __restrict__ out) {
    const int l = blockIdx.x;
    const int pt = blockIdx.y;
    const int t = threadIdx.x;     // 256
    const int pos = t >> 5;        // 0..7
    const int lane = t & 31;
    const int p = pt * 8 + pos;

    __shared__ float sf[8][1537];          // feats per pos: [ch*24+K]
    __shared__ float sxl2[8][LEARN];
    __shared__ float sh[8][FFN_HID];

    for (int idx = t; idx < 1536 * 8; idx += 256) {
        const int row = idx >> 3;
        const int pp = idx & 7;
        sf[pp][row] = dbuf[((size_t)l * 1536 + row) * NLON + pt * 8 + pp];
    }
    __syncthreads();

#pragma unroll
    for (int s2 = 0; s2 < 2; ++s2) {
        const int ch = lane + 32 * s2;
        const int n = ch >> 4;
        float fr[TOTAL_K];
#pragma unroll
        for (int k = 0; k < TOTAL_K; ++k) fr[k] = sf[pos][ch * TOTAL_K + k];
        float ho = hb2[n];
        for (int m = 0; m < HEAD_HID; ++m) {
            float a = hb1[n * HEAD_HID + m];
#pragma unroll
            for (int k = 0; k < TOTAL_K; ++k)
                a = fmaf(fr[k], hw1[(n * TOTAL_K + k) * HEAD_HID + m], a);
            ho = fmaf(gelu_f(a), hw2[n * HEAD_HID + m], ho);
        }
        sxl2[pos][ch] = ho + x[(l * NLON + p) * MODEL_DIM + ch];
    }
    __syncthreads();

    const float sc0 = x[(l * NLON + p) * MODEL_DIM + 64];
    const float sc1 = x[(l * NLON + p) * MODEL_DIM + 65];

#pragma unroll
    for (int mm = 0; mm < 4; ++mm) {
        const int m = lane + 32 * mm;
        float a = fb0[m];
        for (int k = 0; k < LEARN; ++k)
            a = fmaf(sxl2[pos][k], fw0[k * FFN_HID + m], a);
        a = fmaf(sc0, fw0[64 * FFN_HID + m], a);
        a = fmaf(sc1, fw0[65 * FFN_HID + m], a);
        sh[pos][m] = gelu_f(a);
    }
    __syncthreads();

#pragma unroll
    for (int s2 = 0; s2 < 2; ++s2) {
        const int dch = lane + 32 * s2;
        float a = fb1[dch];
        for (int m = 0; m < FFN_HID; ++m)
            a = fmaf(sh[pos][m], fw1[m * LEARN + dch], a);
        out[(l * NLON + p) * MODEL_DIM + dch] = a + sxl2[pos][dch];
    }
    if (lane < 2) out[(l * NLON + p) * MODEL_DIM + 64 + lane] = lane ? sc1 : sc0;
}

extern "C" void kernel_launch(void* const* d_in, const int* in_sizes, int n_in,
                              void* d_out, int out_size, void* d_ws, size_t ws_size,
                              hipStream_t stream) {
    (void)in_sizes; (void)n_in; (void)out_size; (void)ws_size;
    const float* x = (const float*)d_in[0];
    const float* psi[3] = {(const float*)d_in[1], (const float*)d_in[2], (const float*)d_in[3]};
    const float* w[3] = {(const float*)d_in[4], (const float*)d_in[6], (const float*)d_in[8]};
    const float* b[3] = {(const float*)d_in[5], (const float*)d_in[7], (const float*)d_in[9]};
    const float* hw1 = (const float*)d_in[10];
    const float* hb1 = (const float*)d_in[11];
    const float* hw2 = (const float*)d_in[12];
    const float* hb2 = (const float*)d_in[13];
    const float* fw0 = (const float*)d_in[14];
    const float* fb0 = (const float*)d_in[15];
    const float* fw1 = (const float*)d_in[16];
    const float* fb1 = (const float*)d_in[17];
    float* out = (float*)d_out;

    // workspace carve-up (float2 units), ~95 MB total; all offsets 64B-aligned
    float2* Xh = (float2*)d_ws;                 // 64*64*72            = 294912
    float2* Pp = Xh + 294912;                   // 64*20*7*65          = 582400
    float2* bufA = Pp + 582400;                 // 64*8*64*72          = 2359296
    float2* bufB = bufA + 2359296;              // 64*8*64*72
    float* dbuf = (float*)(bufB + 2359296);     // 64*64*24*128 floats
    u64* nzm = (u64*)(dbuf + (size_t)64 * 64 * 24 * 128);   // 448 masks

    k1_fft_x<<<dim3(64 * 64), dim3(128), 0, stream>>>(x, Xh);

    for (int lvl = 0; lvl < 3; ++lvl) {
        k0_mask<<<dim3(448), dim3(256), 0, stream>>>(psi[lvl], nzm);
        k2_dft<<<dim3(448), dim3(128), 0, stream>>>(psi[lvl], nzm, Pp);
        const float2* ob;
        if (lvl == 0) {
            k3_contract<1><<<dim3(520), dim3(64, 8), 0, stream>>>(Pp, Xh, w[0], b[0], nzm, bufA);
            ob = bufA;
        } else if (lvl == 1) {
            k3_contract<8><<<dim3(520), dim3(64, 8), 0, stream>>>(Pp, bufA, w[1], b[1], nzm, bufB);
            ob = bufB;
        } else {
            k3_contract<8><<<dim3(520), dim3(64, 8), 0, stream>>>(Pp, bufB, w[2], b[2], nzm, bufA);
            ob = bufA;
        }
        k4_irfft<<<dim3(4096), dim3(256), 0, stream>>>(ob, dbuf, lvl);
    }

    k5_head_ffn<<<dim3(64, 16), dim3(256), 0, stream>>>(
        dbuf, x, hw1, hb1, hw2, hb2, fw0, fb0, fw1, fb1, out);
}